// Round 3
// baseline (588.015 us; speedup 1.0000x reference)
//
#include <hip/hip_runtime.h>
#include <cstddef>

// SkipGRU on MI355X (gfx950) — round 8.
// Round 7 analysis: kernel is LDS-BW-bound (ratio 1.5 MFMA per ds_read_b128;
// LDS ~750 cyc vs MFMA 466 cyc per CU per kt). Fix = register blocking:
// wave tile 64n x 96c (r=4,c=6 -> ratio 2.4), block tile 128n x 192c,
// 8 waves (512 thr) with 2-way K-SPLIT (ks=0 even chunks, ks=1 odd) so we
// keep 2 waves/SIMD. 1 block/CU, LDS = 4x20KB ring + 64KB reduction = 144KB
// (dynamic + hipFuncSetAttribute). Counted-vmcnt pipeline kept from round 7:
// supersteps of 2 chunks, 5 loads/wave/superstep, steady vmcnt(5),
// 2 barriers/superstep. K-split partials pairwise-reduced via LDS (2 rounds,
// XOR-swizzled, conflict-light).
//
// Layouts (unchanged):
//  xb[t][nb(64)][kt(16)][g(4)][row(64)][8] bf16 granules (16B).
//  Bt[cc(24)][kt(32)][g(4)][col(64)][8]    (cc = 64 gemm-cols).
//  h ping-pong: same granule layout as xb per nb.
// LDS chunk slot (20KB): A 8KB [ah(2)][g(4)][row64][16B] + 3 x B 4KB
//  [g(4)][col64][16B]; part p (0..19) at byte p*1024.

typedef unsigned short u16;
typedef __attribute__((ext_vector_type(8))) short short8;
typedef __attribute__((ext_vector_type(8))) u16 u16x8;
typedef __attribute__((ext_vector_type(4))) float floatx4;

#define MFMA16(a, b, c) __builtin_amdgcn_mfma_f32_16x16x32_bf16((a), (b), (c), 0, 0, 0)

__device__ __forceinline__ u16 f32_to_bf16(float f) {
  union { float f; unsigned int u; } c; c.f = f;
  unsigned int u = c.u + 0x7FFFu + ((c.u >> 16) & 1u);  // RNE
  return (u16)(u >> 16);
}
__device__ __forceinline__ float bf16_to_f32(u16 v) {
  union { unsigned int u; float f; } c; c.u = ((unsigned int)v) << 16;
  return c.f;
}
__device__ __forceinline__ float sigmoidf_(float x) {
  return 1.0f / (1.0f + __expf(-x));
}
__device__ __forceinline__ void gload_lds16(const void* g, void* l) {
  __builtin_amdgcn_global_load_lds(
      (const __attribute__((address_space(1))) unsigned int*)g,
      (__attribute__((address_space(3))) unsigned int*)l, 16, 0, 0);
}

// ---------------------------------------------------------------------------
// pack_x: coalesced. Block = one (t, nb): 64 rows x 512 c. (unchanged)
// ---------------------------------------------------------------------------
__global__ __launch_bounds__(256)
void pack_x(const float* __restrict__ x, u16* __restrict__ xb) {
  __shared__ u16 sm[64 * 512];              // 64KB
  const int t = blockIdx.x >> 6;
  const int nb = blockIdx.x & 63;
  const int tid = threadIdx.x;
#pragma unroll
  for (int it = 0; it < 16; ++it) {
    int idx = it * 256 + tid;
    int row = idx >> 6, ch = idx & 63;      // row 0..63, ch = 8-float chunk
    int xrow = (nb * 2 + (row >> 5)) * 512 + t * 32 + (row & 31);
    const float* src = x + (size_t)xrow * 512 + ch * 8;
    floatx4 va = *(const floatx4*)src;
    floatx4 vb = *(const floatx4*)(src + 4);
    u16x8 pk;
    pk[0] = f32_to_bf16(va[0]); pk[1] = f32_to_bf16(va[1]);
    pk[2] = f32_to_bf16(va[2]); pk[3] = f32_to_bf16(va[3]);
    pk[4] = f32_to_bf16(vb[0]); pk[5] = f32_to_bf16(vb[1]);
    pk[6] = f32_to_bf16(vb[2]); pk[7] = f32_to_bf16(vb[3]);
    *(u16x8*)&sm[row * 512 + (ch ^ (row & 7)) * 8] = pk;
  }
  __syncthreads();
  u16* dst = xb + (size_t)blockIdx.x * 32768;   // blockIdx = t*64+nb = layout order
#pragma unroll
  for (int it = 0; it < 16; ++it) {
    int idx = it * 256 + tid;
    int row = idx & 63, g = (idx >> 6) & 3, kt = idx >> 8;
    int ch = kt * 4 + g;
    u16x8 vv = *(const u16x8*)&sm[row * 512 + (ch ^ (row & 7)) * 8];
    *(u16x8*)(dst + (size_t)idx * 8) = vv;
  }
}

// ---------------------------------------------------------------------------
// pack_Bt: [W;U] -> Bt bf16 [cc(24)][kt(32)][g(4)][col(64)][8] (unchanged)
// ---------------------------------------------------------------------------
__global__ void pack_Bt(const float* __restrict__ W, const float* __restrict__ U,
                        u16* __restrict__ Bt) {
  size_t gid = (size_t)blockIdx.x * 256 + threadIdx.x;   // < 196608
  int col = (int)(gid & 63);
  int g   = (int)((gid >> 6) & 3);
  int kt  = (int)((gid >> 8) & 31);
  int cc  = (int)(gid >> 13);
  int c = cc * 64 + col;
  int k0 = kt * 32 + g * 8;
  u16x8 pk;
#pragma unroll
  for (int j = 0; j < 8; ++j) {
    int k = k0 + j;
    float v = (k < 512) ? W[(size_t)k * 1536 + c] : U[(size_t)(k - 512) * 1536 + c];
    pk[j] = f32_to_bf16(v);
  }
  *(u16x8*)(Bt + gid * 8) = pk;
}

// ---------------------------------------------------------------------------
// gru_step: one GRU timestep. Grid 256 (1 block/CU), 512 threads = 8 waves.
// Block tile 128n x 192c; wave (wy,wx,ks): 64 rows (wy) x 96 cols (wx) with
// K-chunks split even/odd by ks. Superstep s = chunks {2s, 2s+1}.
// ---------------------------------------------------------------------------
__global__ __launch_bounds__(512, 2)
void gru_step(const u16* __restrict__ xb, const u16* __restrict__ Bt,
              const float* __restrict__ bias,
              const u16* __restrict__ h_in, u16* __restrict__ h_out,
              float* __restrict__ out, int t, int first, int last) {
  extern __shared__ char sm[];              // 81920 ring + 65536 reduction
  const int tid = threadIdx.x;
  const int idx = blockIdx.x;               // 0..255
  const int nbb = idx & 31;                 // idx%8 == nbb%8 -> same-nbb on 1 XCD
  const int hb  = idx >> 5;                 // 0..7
  const int w = __builtin_amdgcn_readfirstlane(tid >> 6);  // 0..7, SGPR
  const int lane = tid & 63;
  const int ks = w & 1, wx = (w >> 1) & 1, wy = w >> 2;
  const int q = lane >> 4, lc = lane & 15;

  const u16* xbB0 = xb + (size_t)(t * 64 + nbb * 2) * 32768;
  const u16* htB0 = h_in + (size_t)(nbb * 2) * 32768;

  floatx4 acZ[4][2], acR[4][2], acX[4][2], acH[4][2];
#pragma unroll
  for (int f = 0; f < 4; ++f)
#pragma unroll
    for (int ci = 0; ci < 2; ++ci) {
      acZ[f][ci] = (floatx4){0.f, 0.f, 0.f, 0.f};
      acR[f][ci] = (floatx4){0.f, 0.f, 0.f, 0.f};
      acX[f][ci] = (floatx4){0.f, 0.f, 0.f, 0.f};
      acH[f][ci] = (floatx4){0.f, 0.f, 0.f, 0.f};
    }

  // Stage superstep ss (chunks 2ss, 2ss+1): 40 x 1KB parts, 5 per wave.
  // Part l: chunk c = l/20, p = l%20; p<8 -> A [ah=p>>2][g=p&3], else
  // B [gate=(p-8)>>2][g=(p-8)&3]. LDS dst = slot*20480 + p*1024 (uniform).
  auto stageSS = [&](int ss) {
#pragma unroll
    for (int i = 0; i < 5; ++i) {
      int l = i * 8 + w;
      int c = (l >= 20) ? 1 : 0;
      int p = l - c * 20;
      int kt = ss * 2 + c;
      char* dst = sm + ((size_t)((kt) & 3) * 20480 + (size_t)p * 1024);
      const u16* src;
      if (p < 8) {
        int ah = p >> 2, g = p & 3;
        src = (kt < 16) ? (xbB0 + (size_t)ah * 32768 + (size_t)kt * 2048 + (size_t)g * 512)
                        : (htB0 + (size_t)ah * 32768 + (size_t)(kt - 16) * 2048 + (size_t)g * 512);
      } else {
        int gate = (p - 8) >> 2, g = (p - 8) & 3;
        int cs = gate * 8 + hb;
        src = Bt + (size_t)(cs * 32 + kt) * 2048 + (size_t)g * 512;
      }
      gload_lds16((const char*)src + lane * 16, dst);
    }
  };

  // Compute one chunk from slot; 4 A-frags x (3 gates x 2 col-frags) = 24 MFMA,
  // 10 ds_read_b128. acT compile-time bound at every call site.
  auto compute = [&](int slot, floatx4 (&acT)[4][2]) {
    const char* L = sm + (size_t)slot * 20480;
    const char* Ab = L + wy * 4096 + q * 1024 + lc * 16;
    short8 a0 = *(const short8*)(Ab);
    short8 a1 = *(const short8*)(Ab + 256);
    short8 a2 = *(const short8*)(Ab + 512);
    short8 a3 = *(const short8*)(Ab + 768);
    __builtin_amdgcn_s_setprio(1);
#pragma unroll
    for (int ci = 0; ci < 2; ++ci) {
      const char* Bb = L + 8192 + q * 1024 + (wx * 32 + ci * 16 + lc) * 16;
      short8 bz = *(const short8*)(Bb);
      short8 br = *(const short8*)(Bb + 4096);
      short8 bh = *(const short8*)(Bb + 8192);
      acZ[0][ci] = MFMA16(a0, bz, acZ[0][ci]);
      acZ[1][ci] = MFMA16(a1, bz, acZ[1][ci]);
      acZ[2][ci] = MFMA16(a2, bz, acZ[2][ci]);
      acZ[3][ci] = MFMA16(a3, bz, acZ[3][ci]);
      acR[0][ci] = MFMA16(a0, br, acR[0][ci]);
      acR[1][ci] = MFMA16(a1, br, acR[1][ci]);
      acR[2][ci] = MFMA16(a2, br, acR[2][ci]);
      acR[3][ci] = MFMA16(a3, br, acR[3][ci]);
      acT[0][ci] = MFMA16(a0, bh, acT[0][ci]);
      acT[1][ci] = MFMA16(a1, bh, acT[1][ci]);
      acT[2][ci] = MFMA16(a2, bh, acT[2][ci]);
      acT[3][ci] = MFMA16(a3, bh, acT[3][ci]);
    }
    __builtin_amdgcn_s_setprio(0);
  };

  // ---- Pipeline: supersteps, 1 ahead, counted vmcnt(5), 2 barriers/superstep.
  // iter s: [outstanding: stage(s) 5 + stage(s+1) 5] vmcnt(5) -> stage(s) done;
  // barrier publishes; compute my chunk; barrier (slots of s free);
  // stage(s+2) overwrites them -> in flight across next iter's compute.
  stageSS(0);
  stageSS(1);
  if (first) {
    for (int s = 0; s < 8; ++s) {
      if (s < 7) asm volatile("s_waitcnt vmcnt(5)" ::: "memory");
      else       asm volatile("s_waitcnt vmcnt(0)" ::: "memory");
      __builtin_amdgcn_s_barrier();
      compute((2 * s + ks) & 3, acX);
      __builtin_amdgcn_s_barrier();
      if (s < 6) stageSS(s + 2);
    }
  } else {
    for (int s = 0; s < 8; ++s) {
      asm volatile("s_waitcnt vmcnt(5)" ::: "memory");
      __builtin_amdgcn_s_barrier();
      compute((2 * s + ks) & 3, acX);
      __builtin_amdgcn_s_barrier();
      stageSS(s + 2);                        // 2..9, always valid
    }
    for (int s = 8; s < 16; ++s) {
      if (s < 15) asm volatile("s_waitcnt vmcnt(5)" ::: "memory");
      else        asm volatile("s_waitcnt vmcnt(0)" ::: "memory");
      __builtin_amdgcn_s_barrier();
      compute((2 * s + ks) & 3, acH);
      __builtin_amdgcn_s_barrier();
      if (s < 14) stageSS(s + 2);
    }
  }

  // ---- K-split reduction: ks=1 partials -> ks=0, two 64KB rounds via LDS.
  // Layout per pair (wy,wx): 16KB at red + pp*4096 floats; per lane 64 f32 at
  // lane*64; slot j XOR-swizzled by (lane&15) -> 2-way bank alias only (free).
  __syncthreads();
  float* red = (float*)(sm + 81920);
  float* myred = red + (size_t)(wy * 2 + wx) * 4096 + (size_t)lane * 64;
  if (ks == 1) {
#pragma unroll
    for (int f = 0; f < 4; ++f)
#pragma unroll
      for (int ci = 0; ci < 2; ++ci) {
        int j0 = f * 2 + ci;
        *(floatx4*)(myred + ((j0 ^ (lane & 15)) * 4)) = acZ[f][ci];
        *(floatx4*)(myred + (((8 + j0) ^ (lane & 15)) * 4)) = acR[f][ci];
      }
  }
  __syncthreads();
  if (ks == 0) {
#pragma unroll
    for (int f = 0; f < 4; ++f)
#pragma unroll
      for (int ci = 0; ci < 2; ++ci) {
        int j0 = f * 2 + ci;
        acZ[f][ci] += *(const floatx4*)(myred + ((j0 ^ (lane & 15)) * 4));
        acR[f][ci] += *(const floatx4*)(myred + (((8 + j0) ^ (lane & 15)) * 4));
      }
  }
  __syncthreads();
  if (ks == 1) {
#pragma unroll
    for (int f = 0; f < 4; ++f)
#pragma unroll
      for (int ci = 0; ci < 2; ++ci) {
        int j0 = f * 2 + ci;
        *(floatx4*)(myred + ((j0 ^ (lane & 15)) * 4)) = acX[f][ci];
        *(floatx4*)(myred + (((8 + j0) ^ (lane & 15)) * 4)) = acH[f][ci];
      }
  }
  __syncthreads();
  if (ks == 0) {
#pragma unroll
    for (int f = 0; f < 4; ++f)
#pragma unroll
      for (int ci = 0; ci < 2; ++ci) {
        int j0 = f * 2 + ci;
        acX[f][ci] += *(const floatx4*)(myred + ((j0 ^ (lane & 15)) * 4));
        acH[f][ci] += *(const floatx4*)(myred + (((8 + j0) ^ (lane & 15)) * 4));
      }
  }
  __syncthreads();

  // ---- Epilogue (ks=0 waves). C/D layout: col = lane&15, row = q*4 + reg.
  u16* Ct = (u16*)sm;   // 128 rows x 72 u16 (18KB), ring area is dead now
  if (ks == 0) {
    const float* b0 = bias;
    const float* b1 = bias + 1536;
#pragma unroll
    for (int ci = 0; ci < 2; ++ci) {
      const int hcl = wx * 32 + ci * 16 + lc;    // 0..63
      const int hg = hb * 64 + hcl;              // 0..511
      const float bz = b0[hg] + b1[hg];
      const float br = b0[512 + hg] + b1[512 + hg];
      const float b0h = b0[1024 + hg];
      const float b1h = b1[1024 + hg];
      const int ktg = hg >> 5;
      const int gg = (hg >> 3) & 3;
      const size_t hbase = ((((size_t)(nbb * 2 + wy) * 16 + ktg) * 4 + gg) * 64);
#pragma unroll
      for (int f = 0; f < 4; ++f) {
#pragma unroll
        for (int reg = 0; reg < 4; ++reg) {
          const int nl = wy * 64 + f * 16 + q * 4 + reg;   // 0..127
          const int n = nbb * 128 + nl;
          float z = sigmoidf_(acZ[f][ci][reg] + bz);
          float r = sigmoidf_(acR[f][ci][reg] + br);
          float hh = acX[f][ci][reg] + b0h + r * (acH[f][ci][reg] + b1h);
          hh = fmaxf(hh, 0.0f);
          float hp = 0.0f;
          if (!first) hp = bf16_to_f32(h_in[(hbase + (nl & 63)) * 8 + (hg & 7)]);
          float v = z * hp + (1.0f - z) * hh;
          if (last) out[(size_t)n * 512 + hg] = v;
          else      Ct[nl * 72 + hcl] = f32_to_bf16(v);
        }
      }
    }
  }
  if (!last) {
    __syncthreads();
    // Re-emit h in granule layout: 1024 granules (row128 x gc8), 2/thread.
#pragma unroll
    for (int i = 0; i < 2; ++i) {
      int e = i * 512 + tid;                    // 0..1023
      int row = e & 127, gc = e >> 7;           // gc 0..7
      u16x8 vv = *(const u16x8*)(Ct + row * 72 + gc * 8);
      int nb2 = nbb * 2 + (row >> 6);
      int ktg = hb * 2 + (gc >> 2);
      int g = gc & 3;
      *(u16x8*)(h_out + ((((size_t)nb2 * 16 + ktg) * 4 + g) * 64 + (row & 63)) * 8) = vv;
    }
  }
}

// ---------------------------------------------------------------------------
extern "C" void kernel_launch(void* const* d_in, const int* in_sizes, int n_in,
                              void* d_out, int out_size, void* d_ws, size_t ws_size,
                              hipStream_t stream) {
  const float* x = (const float*)d_in[0];    // (128,512,512)
  const float* W = (const float*)d_in[1];    // (512,1536)
  const float* U = (const float*)d_in[2];    // (512,1536)
  const float* bias = (const float*)d_in[3]; // (2,1536)
  float* out = (float*)d_out;                // (128,16384)

  u16* xb = (u16*)d_ws;                      // 16*64*32768 u16 = 64 MB
  u16* Bt = xb + (size_t)16 * 64 * 32768;    // 3 MB
  u16* h0 = Bt + (size_t)1536 * 1024;        // 4 MB
  u16* h1 = h0 + (size_t)4096 * 512;         // 4 MB

  static int attr_set = 0;
  if (!attr_set) {
    hipFuncSetAttribute((const void*)gru_step,
                        hipFuncAttributeMaxDynamicSharedMemorySize, 147456);
    attr_set = 1;
  }

  pack_x<<<1024, 256, 0, stream>>>(x, xb);
  pack_Bt<<<768, 256, 0, stream>>>(W, U, Bt);

  for (int t = 0; t < 16; ++t) {
    const u16* hin = (t & 1) ? h1 : h0;      // t=0 never reads h
    u16* hout = (t & 1) ? h0 : h1;
    gru_step<<<256, 512, 147456, stream>>>(
        xb, Bt, bias, hin, hout, out, t, (t == 0) ? 1 : 0, (t == 15) ? 1 : 0);
  }
}

// Round 4
// 508.897 us; speedup vs baseline: 1.1555x; 1.1555x over previous
//
#include <hip/hip_runtime.h>
#include <cstddef>

// SkipGRU on MI355X (gfx950) — round 9.
// = round 7 EXACTLY (best: 503.6us — 64n x 192c tile, 4 waves, 4x16KB ring,
//   2 blocks/CU, readfirstlane wave id, counted pipeline) with ONE change:
//   the K-loop processes CHUNK PAIRS per barrier interval.
//     stage(pair s+1) ; compute(2s) ; compute(2s+1) ; __syncthreads()
//   Pairs alternate slot sets {0,1}/{2,3}, so staging targets slots freed at
//   the PREVIOUS barrier -> one barrier per pair (16+1 per step vs 32),
//   double the MFMA/ds_read work per sync interval. The __syncthreads()
//   vmcnt(0) drain is cheap: drained loads were issued a full compute
//   interval (~2 chunks) earlier.
// Round-8 post-mortem: neither MFMA (930cyc) nor LDS (~1000cyc) saturated at
// ~1800cyc/pair -> latency/sync-bound, so barrier RATE is the lever; the
// 8-wave/K-split restructure attacked the wrong term and regressed.
//
// Layouts (unchanged):
//  xb[t][nb(64)][kt(16)][g(4)][row(64)][8] bf16 granules (16B).
//  Bt[cc(24)][kt(32)][g(4)][col(64)][8]    (cc = 64 gemm-cols).
//  h ping-pong: same granule layout as xb per nb.

typedef unsigned short u16;
typedef __attribute__((ext_vector_type(8))) short short8;
typedef __attribute__((ext_vector_type(8))) u16 u16x8;
typedef __attribute__((ext_vector_type(4))) float floatx4;

#define MFMA16(a, b, c) __builtin_amdgcn_mfma_f32_16x16x32_bf16((a), (b), (c), 0, 0, 0)

__device__ __forceinline__ u16 f32_to_bf16(float f) {
  union { float f; unsigned int u; } c; c.f = f;
  unsigned int u = c.u + 0x7FFFu + ((c.u >> 16) & 1u);  // RNE
  return (u16)(u >> 16);
}
__device__ __forceinline__ float bf16_to_f32(u16 v) {
  union { unsigned int u; float f; } c; c.u = ((unsigned int)v) << 16;
  return c.f;
}
__device__ __forceinline__ float sigmoidf_(float x) {
  return 1.0f / (1.0f + __expf(-x));
}
__device__ __forceinline__ void gload_lds16(const void* g, void* l) {
  __builtin_amdgcn_global_load_lds(
      (const __attribute__((address_space(1))) unsigned int*)g,
      (__attribute__((address_space(3))) unsigned int*)l, 16, 0, 0);
}

// ---------------------------------------------------------------------------
// pack_x: coalesced. Block = one (t, nb): 64 rows x 512 c. (unchanged)
// ---------------------------------------------------------------------------
__global__ __launch_bounds__(256)
void pack_x(const float* __restrict__ x, u16* __restrict__ xb) {
  __shared__ u16 sm[64 * 512];              // 64KB
  const int t = blockIdx.x >> 6;
  const int nb = blockIdx.x & 63;
  const int tid = threadIdx.x;
#pragma unroll
  for (int it = 0; it < 16; ++it) {
    int idx = it * 256 + tid;
    int row = idx >> 6, ch = idx & 63;      // row 0..63, ch = 8-float chunk
    int xrow = (nb * 2 + (row >> 5)) * 512 + t * 32 + (row & 31);
    const float* src = x + (size_t)xrow * 512 + ch * 8;
    floatx4 va = *(const floatx4*)src;
    floatx4 vb = *(const floatx4*)(src + 4);
    u16x8 pk;
    pk[0] = f32_to_bf16(va[0]); pk[1] = f32_to_bf16(va[1]);
    pk[2] = f32_to_bf16(va[2]); pk[3] = f32_to_bf16(va[3]);
    pk[4] = f32_to_bf16(vb[0]); pk[5] = f32_to_bf16(vb[1]);
    pk[6] = f32_to_bf16(vb[2]); pk[7] = f32_to_bf16(vb[3]);
    *(u16x8*)&sm[row * 512 + (ch ^ (row & 7)) * 8] = pk;
  }
  __syncthreads();
  u16* dst = xb + (size_t)blockIdx.x * 32768;   // blockIdx = t*64+nb = layout order
#pragma unroll
  for (int it = 0; it < 16; ++it) {
    int idx = it * 256 + tid;
    int row = idx & 63, g = (idx >> 6) & 3, kt = idx >> 8;
    int ch = kt * 4 + g;
    u16x8 vv = *(const u16x8*)&sm[row * 512 + (ch ^ (row & 7)) * 8];
    *(u16x8*)(dst + (size_t)idx * 8) = vv;
  }
}

// ---------------------------------------------------------------------------
// pack_Bt: [W;U] -> Bt bf16 [cc(24)][kt(32)][g(4)][col(64)][8] (unchanged)
// ---------------------------------------------------------------------------
__global__ void pack_Bt(const float* __restrict__ W, const float* __restrict__ U,
                        u16* __restrict__ Bt) {
  size_t gid = (size_t)blockIdx.x * 256 + threadIdx.x;   // < 196608
  int col = (int)(gid & 63);
  int g   = (int)((gid >> 6) & 3);
  int kt  = (int)((gid >> 8) & 31);
  int cc  = (int)(gid >> 13);
  int c = cc * 64 + col;
  int k0 = kt * 32 + g * 8;
  u16x8 pk;
#pragma unroll
  for (int j = 0; j < 8; ++j) {
    int k = k0 + j;
    float v = (k < 512) ? W[(size_t)k * 1536 + c] : U[(size_t)(k - 512) * 1536 + c];
    pk[j] = f32_to_bf16(v);
  }
  *(u16x8*)(Bt + gid * 8) = pk;
}

// ---------------------------------------------------------------------------
// gru_step: one GRU timestep.
// Grid 512 linear, XCD-swizzled: nb = (idx>>6)*8 + (idx&7), hb = (idx>>3)&7.
// Block tile 64n x 192c; 4 waves (wy,wx); wave = 32n x (3 gates x 32 h-cols).
// LDS: 4 x 16KB ring. K-loop: chunk-PAIR intervals, 1 __syncthreads per pair.
// ---------------------------------------------------------------------------
__global__ __launch_bounds__(256)
void gru_step(const u16* __restrict__ xb, const u16* __restrict__ Bt,
              const float* __restrict__ bias,
              const u16* __restrict__ h_in, u16* __restrict__ h_out,
              float* __restrict__ out, int t, int first, int last) {
  __shared__ alignas(16) char sm[65536];    // 4 x 16KB ring -> 2 blocks/CU
  const int tid = threadIdx.x;
  const int idx = blockIdx.x;
  const int nb = ((idx >> 6) << 3) | (idx & 7);   // 0..63
  const int hb = (idx >> 3) & 7;                  // 0..7
  // WAVE-UNIFORM wave id: forces SGPR so global_load_lds LDS destinations are
  // provably uniform (no compiler waterfall around each load).
  const int w = __builtin_amdgcn_readfirstlane(tid >> 6);
  const int lane = tid & 63;
  const int wy = w >> 1, wx = w & 1;              // scalar
  const int q = lane >> 4, lc = lane & 15;

  const u16* xbB = xb + (size_t)(t * 64 + nb) * 32768;
  const u16* htB = h_in + (size_t)nb * 32768;
  const int cs0 = hb, cs1 = 8 + hb, cs2 = 16 + hb;   // z / r / h-gate col-chunks

  floatx4 acZ[2][2] = {{{0.f,0.f,0.f,0.f},{0.f,0.f,0.f,0.f}},{{0.f,0.f,0.f,0.f},{0.f,0.f,0.f,0.f}}};
  floatx4 acR[2][2] = {{{0.f,0.f,0.f,0.f},{0.f,0.f,0.f,0.f}},{{0.f,0.f,0.f,0.f},{0.f,0.f,0.f,0.f}}};
  floatx4 acX[2][2] = {{{0.f,0.f,0.f,0.f},{0.f,0.f,0.f,0.f}},{{0.f,0.f,0.f,0.f},{0.f,0.f,0.f,0.f}}};
  floatx4 acH[2][2] = {{{0.f,0.f,0.f,0.f},{0.f,0.f,0.f,0.f}},{{0.f,0.f,0.f,0.f},{0.f,0.f,0.f,0.f}}};

  const int wo = w * 1024;   // SGPR: per-wave byte slot within each 4KB panel

  // Stage K-chunk kt (A 4KB + 3 gate-B 4KB) into ring slot kt&3. 4 glds16/wave.
  auto stage = [&](int kt) {
    char* lds = sm + (kt & 3) * 16384;        // scalar -> uniform base
    const char* aS = (const char*)((kt < 16) ? (xbB + (size_t)kt * 2048)
                                             : (htB + (size_t)(kt - 16) * 2048));
    gload_lds16(aS + wo + lane * 16, lds + wo);
    gload_lds16((const char*)(Bt + (size_t)(cs0 * 32 + kt) * 2048) + wo + lane * 16,
                lds + 4096 + wo);
    gload_lds16((const char*)(Bt + (size_t)(cs1 * 32 + kt) * 2048) + wo + lane * 16,
                lds + 8192 + wo);
    gload_lds16((const char*)(Bt + (size_t)(cs2 * 32 + kt) * 2048) + wo + lane * 16,
                lds + 12288 + wo);
  };

  // Compute one K-chunk from ring slot; acT compile-time bound per call site.
  auto compute = [&](int slot, floatx4 (&acT)[2][2]) {
    const char* lds = sm + slot * 16384;
    short8 a0 = *(const short8*)(lds + (q * 64 + wy * 32 + lc) * 16);
    short8 a1 = *(const short8*)(lds + (q * 64 + wy * 32 + 16 + lc) * 16);
#pragma unroll
    for (int ci = 0; ci < 2; ++ci) {
      int co = (q * 64 + wx * 32 + ci * 16 + lc) * 16;
      short8 bz = *(const short8*)(lds + 4096 + co);
      short8 br = *(const short8*)(lds + 8192 + co);
      short8 bh = *(const short8*)(lds + 12288 + co);
      acZ[0][ci] = MFMA16(a0, bz, acZ[0][ci]);
      acZ[1][ci] = MFMA16(a1, bz, acZ[1][ci]);
      acR[0][ci] = MFMA16(a0, br, acR[0][ci]);
      acR[1][ci] = MFMA16(a1, br, acR[1][ci]);
      acT[0][ci] = MFMA16(a0, bh, acT[0][ci]);
      acT[1][ci] = MFMA16(a1, bh, acT[1][ci]);
    }
  };

  // ---- K-loop over chunk PAIRS: one __syncthreads() per pair.
  // Pair s = chunks {2s, 2s+1} in slots {(2s)&3, (2s+1)&3} — alternating
  // {0,1}/{2,3}. stage(pair s+1) targets the OTHER slot set, freed at the
  // previous barrier. The barrier's vmcnt(0) drain only hits loads issued a
  // full pair-compute (~2 chunks) earlier.
  stage(0); stage(1);
  __syncthreads();                            // pair 0 resident
  if (first) {
    // 16 chunks = 8 pairs, acc acX.
    for (int s = 0; s < 8; ++s) {
      if (s < 7) { stage(2 * s + 2); stage(2 * s + 3); }
      __builtin_amdgcn_s_setprio(1);
      compute((2 * s) & 3, acX);
      compute((2 * s + 1) & 3, acX);
      __builtin_amdgcn_s_setprio(0);
      __syncthreads();
    }
  } else {
    // Phase 0: pairs 0..7 (chunks 0..15), acc acX; prefetch runs into phase 1.
    for (int s = 0; s < 8; ++s) {
      stage(2 * s + 2); stage(2 * s + 3);     // chunks 2..17, always valid
      __builtin_amdgcn_s_setprio(1);
      compute((2 * s) & 3, acX);
      compute((2 * s + 1) & 3, acX);
      __builtin_amdgcn_s_setprio(0);
      __syncthreads();
    }
    // Phase 1: pairs 8..15 (chunks 16..31), acc acH.
    for (int s = 8; s < 16; ++s) {
      if (s < 15) { stage(2 * s + 2); stage(2 * s + 3); }
      __builtin_amdgcn_s_setprio(1);
      compute((2 * s) & 3, acH);
      compute((2 * s + 1) & 3, acH);
      __builtin_amdgcn_s_setprio(0);
      __syncthreads();
    }
  }

  // ---- Epilogue. C/D layout: col = lane&15, row = quad*4 + reg ----
  // (final loop barrier already synced; sm reuse below is safe)
  const float* b0 = bias;
  const float* b1 = bias + 1536;
  u16* Ct = (u16*)sm;    // 64 rows x 72 u16 (9KB)
#pragma unroll
  for (int ci = 0; ci < 2; ++ci) {
    const int hcl = wx * 32 + ci * 16 + lc;    // 0..63
    const int hg = hb * 64 + hcl;              // 0..511
    const float bz = b0[hg] + b1[hg];
    const float br = b0[512 + hg] + b1[512 + hg];
    const float b0h = b0[1024 + hg];
    const float b1h = b1[1024 + hg];
    const int ktg = hg >> 5;
    const int gg = (hg >> 3) & 3;
    const size_t hbase = (((size_t)nb * 16 + ktg) * 4 + gg) * 64;
#pragma unroll
    for (int mi = 0; mi < 2; ++mi) {
#pragma unroll
      for (int reg = 0; reg < 4; ++reg) {
        const int nl = wy * 32 + mi * 16 + q * 4 + reg;   // 0..63
        const int n = nb * 64 + nl;
        float z = sigmoidf_(acZ[mi][ci][reg] + bz);
        float r = sigmoidf_(acR[mi][ci][reg] + br);
        float hh = acX[mi][ci][reg] + b0h + r * (acH[mi][ci][reg] + b1h);
        hh = fmaxf(hh, 0.0f);
        float hp = 0.0f;
        if (!first) hp = bf16_to_f32(h_in[(hbase + nl) * 8 + (hg & 7)]);
        float v = z * hp + (1.0f - z) * hh;
        if (last) out[(size_t)n * 512 + hg] = v;
        else      Ct[nl * 72 + hcl] = f32_to_bf16(v);
      }
    }
  }
  if (!last) {
    __syncthreads();
    // Re-emit h in granule layout: 512 granules (row64 x g4 x ktl2), 2/thread.
#pragma unroll
    for (int i = 0; i < 2; ++i) {
      int e = i * 256 + tid;
      int row = e & 63;
      int g = (e >> 6) & 3;
      int ktl = e >> 8;                         // 0..1
      u16x8 vv = *(const u16x8*)(Ct + row * 72 + ktl * 32 + g * 8);
      *(u16x8*)(h_out + ((((size_t)nb * 16 + (hb * 2 + ktl)) * 4 + g) * 64 + row) * 8) = vv;
    }
  }
}

// ---------------------------------------------------------------------------
extern "C" void kernel_launch(void* const* d_in, const int* in_sizes, int n_in,
                              void* d_out, int out_size, void* d_ws, size_t ws_size,
                              hipStream_t stream) {
  const float* x = (const float*)d_in[0];    // (128,512,512)
  const float* W = (const float*)d_in[1];    // (512,1536)
  const float* U = (const float*)d_in[2];    // (512,1536)
  const float* bias = (const float*)d_in[3]; // (2,1536)
  float* out = (float*)d_out;                // (128,16384)

  u16* xb = (u16*)d_ws;                      // 16*64*32768 u16 = 64 MB
  u16* Bt = xb + (size_t)16 * 64 * 32768;    // 3 MB
  u16* h0 = Bt + (size_t)1536 * 1024;        // 4 MB
  u16* h1 = h0 + (size_t)4096 * 512;         // 4 MB

  pack_x<<<1024, 256, 0, stream>>>(x, xb);
  pack_Bt<<<768, 256, 0, stream>>>(W, U, Bt);

  for (int t = 0; t < 16; ++t) {
    const u16* hin = (t & 1) ? h1 : h0;      // t=0 never reads h
    u16* hout = (t & 1) ? h0 : h1;
    gru_step<<<512, 256, 0, stream>>>(
        xb, Bt, bias, hin, hout, out, t, (t == 0) ? 1 : 0, (t == 15) ? 1 : 0);
  }
}